// Round 2
// baseline (710.268 us; speedup 1.0000x reference)
//
#include <hip/hip_runtime.h>

// Problem constants (T, B, D) from setup_inputs(): x is [T, B, D] fp32.
constexpr int T_DIM = 512;
constexpr int B_DIM = 32;
constexpr int D_DIM = 512;
constexpr int MBD   = B_DIM * D_DIM;          // 16384, row stride of [T, B*D]
constexpr long TBD  = (long)T_DIM * MBD;      // 8388608 elements per [T,B,D] tensor

#define BM 128
#define BN 128
#define BK 16

// Generic tiled fp32 GEMM:
//   C[m,n] = sum_k A[m,k] * B'[k,n] (+ bias[n])
// A is [M,K] row-major with row stride lda.
// If BT: B is [N,K] row-major (we compute A·B^T), row stride ldb.
// else : B is [K,N] row-major, row stride ldb.
// blockIdx.z selects batch via strideA/strideB/strideC element offsets.
// All of M, N, K must be multiples of the tile dims (true for this problem).
template<bool BT, bool HAS_BIAS>
__global__ __launch_bounds__(256)
void gemm_k(const float* __restrict__ A, long lda, long strideA,
            const float* __restrict__ Bm, long ldb, long strideB,
            const float* __restrict__ bias,
            float* __restrict__ C, long ldc, long strideC,
            int K)
{
    // +4 pad keeps float4 alignment (row stride 132 floats = 528 B, 16B-aligned)
    // and breaks the k-major bank aliasing on the transpose writes.
    __shared__ float As[BK][BM + 4];
    __shared__ float Bs[BK][BN + 4];

    const int tid = threadIdx.x;
    const int tx  = tid & 15;   // n-direction (16)
    const int ty  = tid >> 4;   // m-direction (16)

    const long bm = (long)blockIdx.y * BM;
    const long bn = (long)blockIdx.x * BN;

    A  += (long)blockIdx.z * strideA;
    Bm += (long)blockIdx.z * strideB;
    C  += (long)blockIdx.z * strideC;

    float acc[8][8];
#pragma unroll
    for (int i = 0; i < 8; i++)
#pragma unroll
        for (int j = 0; j < 8; j++) acc[i][j] = 0.f;

    const int ar = tid >> 2;          // 0..63  (row within tile)
    const int ac = (tid & 3) << 2;    // 0,4,8,12 (k within tile)
    const int br = tid >> 5;          // 0..7
    const int bc = (tid & 31) << 2;   // 0..124

    for (int k0 = 0; k0 < K; k0 += BK) {
        // ---- A tile: [BM x BK] -> As[k][m] (transposed store, scalar writes)
#pragma unroll
        for (int i = 0; i < 2; i++) {
            const int r = ar + i * 64;
            const float4 av = *(const float4*)(A + (bm + r) * lda + k0 + ac);
            As[ac + 0][r] = av.x;
            As[ac + 1][r] = av.y;
            As[ac + 2][r] = av.z;
            As[ac + 3][r] = av.w;
        }
        // ---- B tile
        if (BT) {
            // B is [N,K]: need Bs[k][n] = B[bn+n][k0+k] — transpose like A
#pragma unroll
            for (int i = 0; i < 2; i++) {
                const int r = ar + i * 64;
                const float4 bv = *(const float4*)(Bm + (bn + r) * ldb + k0 + ac);
                Bs[ac + 0][r] = bv.x;
                Bs[ac + 1][r] = bv.y;
                Bs[ac + 2][r] = bv.z;
                Bs[ac + 3][r] = bv.w;
            }
        } else {
            // B is [K,N]: direct float4 copy
#pragma unroll
            for (int i = 0; i < 2; i++) {
                const int r = br + i * 8;
                const float4 bv = *(const float4*)(Bm + (k0 + r) * ldb + bn + bc);
                *(float4*)&Bs[r][bc] = bv;
            }
        }
        __syncthreads();

#pragma unroll
        for (int k = 0; k < BK; k++) {
            float a[8], b[8];
            // split 4+4 from the two 64-wide halves: 2-way-max bank aliasing (free)
            *(float4*)&a[0] = *(const float4*)&As[k][ty * 4];
            *(float4*)&a[4] = *(const float4*)&As[k][64 + ty * 4];
            *(float4*)&b[0] = *(const float4*)&Bs[k][tx * 4];
            *(float4*)&b[4] = *(const float4*)&Bs[k][64 + tx * 4];
#pragma unroll
            for (int i = 0; i < 8; i++)
#pragma unroll
                for (int j = 0; j < 8; j++)
                    acc[i][j] = fmaf(a[i], b[j], acc[i][j]);
        }
        __syncthreads();
    }

    float4 bias0 = {0.f, 0.f, 0.f, 0.f}, bias1 = {0.f, 0.f, 0.f, 0.f};
    if (HAS_BIAS) {
        bias0 = *(const float4*)(bias + bn + tx * 4);
        bias1 = *(const float4*)(bias + bn + 64 + tx * 4);
    }

#pragma unroll
    for (int i = 0; i < 8; i++) {
        const long row = bm + ((i < 4) ? (ty * 4 + i) : (64 + ty * 4 + (i - 4)));
        float4 c0, c1;
        c0.x = acc[i][0] + bias0.x;
        c0.y = acc[i][1] + bias0.y;
        c0.z = acc[i][2] + bias0.z;
        c0.w = acc[i][3] + bias0.w;
        c1.x = acc[i][4] + bias1.x;
        c1.y = acc[i][5] + bias1.y;
        c1.z = acc[i][6] + bias1.z;
        c1.w = acc[i][7] + bias1.w;
        *(float4*)(C + row * ldc + bn + tx * 4)      = c0;
        *(float4*)(C + row * ldc + bn + 64 + tx * 4) = c1;
    }
}

// Integrate-and-fire scan over leading time dim, in place.
// Y layout: [T, B*D] with row stride MBD. One thread per (b,d) chain.
// Only B*D = 16384 threads exist -> latency-bound, so software-pipeline the
// loads: batch of 8 in flight while the previous 8 serial VALU steps retire.
// h = vmem + x_t; s = (h >= 1); y_t = s; vmem = s ? 0 : h   (hard reset)
__global__ __launch_bounds__(256)
void if_scan_k(float* __restrict__ Y)
{
    const int idx = blockIdx.x * blockDim.x + threadIdx.x; // 0..MBD-1
    float* p = Y + idx;
    float vmem = 0.f;

    float cur[8], nxt[8];
#pragma unroll
    for (int j = 0; j < 8; j++) cur[j] = p[(long)j * MBD];

#pragma unroll 1
    for (int t = 0; t < T_DIM; t += 8) {
        // issue next batch's loads before touching cur (they overlap the VALU chain)
        if (t + 8 < T_DIM) {
#pragma unroll
            for (int j = 0; j < 8; j++) nxt[j] = p[(long)(t + 8 + j) * MBD];
        }
#pragma unroll
        for (int j = 0; j < 8; j++) {
            const float h = vmem + cur[j];
            const bool fire = (h >= 1.f);
            p[(long)(t + j) * MBD] = fire ? 1.f : 0.f;
            vmem = fire ? 0.f : h;
        }
#pragma unroll
        for (int j = 0; j < 8; j++) cur[j] = nxt[j];
    }
}

extern "C" void kernel_launch(void* const* d_in, const int* in_sizes, int n_in,
                              void* d_out, int out_size, void* d_ws, size_t ws_size,
                              hipStream_t stream)
{
    const float* x  = (const float*)d_in[0];
    const float* Wq = (const float*)d_in[1];
    const float* bq = (const float*)d_in[2];
    const float* Wk = (const float*)d_in[3];
    const float* bk = (const float*)d_in[4];
    const float* Wv = (const float*)d_in[5];
    const float* bv = (const float*)d_in[6];
    float* out = (float*)d_out;

    // Workspace layout (all fp32): q | k | v | attn  = 4 * 32 MiB = 128 MiB
    float* q    = (float*)d_ws;
    float* kbuf = q    + TBD;
    float* vbuf = kbuf + TBD;
    float* attn = vbuf + TBD;   // [B][T][T]

    const dim3 blk(256);

    // 1) q/k/v pre-activations: [T*B, D] = x[T*B, D] @ W^T + b
    const dim3 g1(D_DIM / BN, (T_DIM * B_DIM) / BM, 1);
    gemm_k<true, true><<<g1, blk, 0, stream>>>(x, D_DIM, 0, Wq, D_DIM, 0, bq,
                                               q, D_DIM, 0, D_DIM);
    gemm_k<true, true><<<g1, blk, 0, stream>>>(x, D_DIM, 0, Wk, D_DIM, 0, bk,
                                               kbuf, D_DIM, 0, D_DIM);
    gemm_k<true, true><<<g1, blk, 0, stream>>>(x, D_DIM, 0, Wv, D_DIM, 0, bv,
                                               vbuf, D_DIM, 0, D_DIM);

    // 2) IF scans on q and v (in place; k is NOT spiked)
    if_scan_k<<<MBD / 256, blk, 0, stream>>>(q);
    if_scan_k<<<MBD / 256, blk, 0, stream>>>(vbuf);

    // 3) attn[b] = Q_b [T,D] @ K_b^T [D,T]  -> attn [B][T][T]
    const dim3 g3(T_DIM / BN, T_DIM / BM, B_DIM);
    gemm_k<true, false><<<g3, blk, 0, stream>>>(
        q,    MBD, D_DIM,                // A: rows stride B*D, batch offset b*D
        kbuf, MBD, D_DIM,                // B (transposed use)
        nullptr,
        attn, T_DIM, (long)T_DIM * T_DIM,
        D_DIM);

    // 4) Z[b] = attn_b [T,T] @ V_b [T,D] -> out [T, B, D]
    gemm_k<false, false><<<g3, blk, 0, stream>>>(
        attn, T_DIM, (long)T_DIM * T_DIM,
        vbuf, MBD, D_DIM,
        nullptr,
        out, MBD, D_DIM,
        T_DIM);

    // 5) final IF scan over time on out (in place)
    if_scan_k<<<MBD / 256, blk, 0, stream>>>(out);
}